// Round 1
// baseline (22148.689 us; speedup 1.0000x reference)
//
#include <hip/hip_runtime.h>
#include <hip/hip_bf16.h>
#include <math.h>

#define T_LEN 8192
#define RCH   512
#define SCH   256
#define QCH   256
#define ACH   28
#define NLAYER 30

// ---------------------------------------------------------------------------
// zero-fill (skip accumulator lives in d_out; must be zeroed every call)
__global__ void zero_kernel(float4* __restrict__ p) {
    p[blockIdx.x * blockDim.x + threadIdx.x] = make_float4(0.f, 0.f, 0.f, 0.f);
}

// ---------------------------------------------------------------------------
// embedding: out[r][t] = Wc[r, x[t-1], 0] + Wc[r, x[t], 1] + bc[r]
__global__ void embed_kernel(const int* __restrict__ x,
                             const float* __restrict__ Wc,
                             const float* __restrict__ bc,
                             float* __restrict__ out) {
    int idx = blockIdx.x * blockDim.x + threadIdx.x;  // over R*T, t fastest
    int r = idx / T_LEN;
    int t = idx - r * T_LEN;
    int xq1 = x[t];
    float v = Wc[((size_t)r * QCH + xq1) * 2 + 1] + bc[r];
    if (t > 0) {
        int xq0 = x[t - 1];
        v += Wc[((size_t)r * QCH + xq0) * 2 + 0];
    }
    out[(size_t)r * T_LEN + t] = v;
}

// ---------------------------------------------------------------------------
// gate kernel: computes g = sigmoid(s) * tanh(t) for one layer.
//   s = Wds(*)out (dilated, K=2) + Was@h + bds + bas
//   t = Wdt(*)out (dilated, K=2) + Wat@h + bdt + bat
// Tile: 64 g-rows x 64 time-cols per WG, 256 threads, 4x4 micro-tile for BOTH
// s and t (shared B tile). K-loop over 512 residual channels, both taps per
// iteration, then a zero-padded 28-wide aux segment.
__global__ __launch_bounds__(256) void gate_kernel(
    const float* __restrict__ outp,   // [512][T]
    const float* __restrict__ h,      // [28][T]
    const float* __restrict__ Wds,    // layer base: [512][512][2]
    const float* __restrict__ Wdt,
    const float* __restrict__ Was,    // [512][28]
    const float* __restrict__ Wat,
    const float* __restrict__ bds, const float* __restrict__ bdt,
    const float* __restrict__ bas, const float* __restrict__ bat,
    float* __restrict__ g,            // [512][T]
    int dil)
{
    __shared__ float As0[16][68];  // [k][m] tap0 s-weights (transposed)
    __shared__ float As1[16][68];  // tap1
    __shared__ float At0[16][68];  // t-branch
    __shared__ float At1[16][68];
    __shared__ float B0[16][68];   // out[c][t-dil]
    __shared__ float B1[16][68];   // out[c][t]

    const int tid  = threadIdx.x;
    const int m0   = blockIdx.x * 64;
    const int t0   = blockIdx.y * 64;
    const int tc   = tid & 15, tr = tid >> 4;
    const int col0 = tc * 4,  row0 = tr * 4;

    // staging maps
    const int mA  = tid >> 2;         // 0..63  (A rows)
    const int kA  = (tid & 3) * 4;    // k offset 0/4/8/12
    const int ttB = tid & 63;         // B cols
    const int kB0 = tid >> 6;         // 0..3

    float accS[4][4] = {{0.f}};
    float accT[4][4] = {{0.f}};

    // ---- main K loop over residual channels (both taps at once) ----
    for (int kb = 0; kb < RCH; kb += 16) {
        {
            const float* ws = Wds + (((size_t)(m0 + mA) * RCH + kb + kA) * 2);
            const float* wt = Wdt + (((size_t)(m0 + mA) * RCH + kb + kA) * 2);
            float4 s0 = *(const float4*)(ws);
            float4 s1 = *(const float4*)(ws + 4);
            float4 t0v = *(const float4*)(wt);
            float4 t1v = *(const float4*)(wt + 4);
            As0[kA + 0][mA] = s0.x; As1[kA + 0][mA] = s0.y;
            As0[kA + 1][mA] = s0.z; As1[kA + 1][mA] = s0.w;
            As0[kA + 2][mA] = s1.x; As1[kA + 2][mA] = s1.y;
            As0[kA + 3][mA] = s1.z; As1[kA + 3][mA] = s1.w;
            At0[kA + 0][mA] = t0v.x; At1[kA + 0][mA] = t0v.y;
            At0[kA + 1][mA] = t0v.z; At1[kA + 1][mA] = t0v.w;
            At0[kA + 2][mA] = t1v.x; At1[kA + 2][mA] = t1v.y;
            At0[kA + 3][mA] = t1v.z; At1[kA + 3][mA] = t1v.w;
        }
        #pragma unroll
        for (int j = 0; j < 4; ++j) {
            int k = kB0 + j * 4;
            int c = kb + k;
            int tg = t0 + ttB;
            int ts = tg - dil;
            B0[k][ttB] = (ts >= 0) ? outp[(size_t)c * T_LEN + ts] : 0.f;
            B1[k][ttB] = outp[(size_t)c * T_LEN + tg];
        }
        __syncthreads();
        #pragma unroll
        for (int kk = 0; kk < 16; ++kk) {
            float a0[4], a1[4], c0[4], c1[4], b0[4], b1[4];
            *(float4*)a0 = *(const float4*)&As0[kk][row0];
            *(float4*)a1 = *(const float4*)&As1[kk][row0];
            *(float4*)c0 = *(const float4*)&At0[kk][row0];
            *(float4*)c1 = *(const float4*)&At1[kk][row0];
            *(float4*)b0 = *(const float4*)&B0[kk][col0];
            *(float4*)b1 = *(const float4*)&B1[kk][col0];
            #pragma unroll
            for (int i = 0; i < 4; ++i)
                #pragma unroll
                for (int j = 0; j < 4; ++j) {
                    accS[i][j] += a0[i] * b0[j] + a1[i] * b1[j];
                    accT[i][j] += c0[i] * b0[j] + c1[i] * b1[j];
                }
        }
        __syncthreads();
    }

    // ---- aux segment: K = 28 (two zero-padded chunks of 16) ----
    for (int kb = 0; kb < 32; kb += 16) {
        #pragma unroll
        for (int j = 0; j < 4; ++j) {
            int a = kb + kA + j;
            float vs = 0.f, vt = 0.f;
            if (a < ACH) {
                vs = Was[(size_t)(m0 + mA) * ACH + a];
                vt = Wat[(size_t)(m0 + mA) * ACH + a];
            }
            As0[kA + j][mA] = vs;
            At0[kA + j][mA] = vt;
        }
        #pragma unroll
        for (int j = 0; j < 4; ++j) {
            int k = kB0 + j * 4;
            int a = kb + k;
            B0[k][ttB] = (a < ACH) ? h[(size_t)a * T_LEN + t0 + ttB] : 0.f;
        }
        __syncthreads();
        #pragma unroll
        for (int kk = 0; kk < 16; ++kk) {
            float av[4], cv[4], bv[4];
            *(float4*)av = *(const float4*)&As0[kk][row0];
            *(float4*)cv = *(const float4*)&At0[kk][row0];
            *(float4*)bv = *(const float4*)&B0[kk][col0];
            #pragma unroll
            for (int i = 0; i < 4; ++i)
                #pragma unroll
                for (int j = 0; j < 4; ++j) {
                    accS[i][j] += av[i] * bv[j];
                    accT[i][j] += cv[i] * bv[j];
                }
        }
        __syncthreads();
    }

    // ---- epilogue: gating, write g ----
    #pragma unroll
    for (int i = 0; i < 4; ++i) {
        int m = m0 + row0 + i;
        float bs = bds[m] + bas[m];
        float bt = bdt[m] + bat[m];
        float4 gv;
        float* gp = (float*)&gv;
        #pragma unroll
        for (int j = 0; j < 4; ++j) {
            float sv = accS[i][j] + bs;
            float tv = accT[i][j] + bt;
            float sig = 1.0f / (1.0f + __expf(-sv));
            gp[j] = sig * tanhf(tv);
        }
        *(float4*)&g[(size_t)m * T_LEN + t0 + col0] = gv;
    }
}

// ---------------------------------------------------------------------------
// skip/res kernel: rows 0..255 -> skip_sum += Wsk@g + bsk
//                  rows 256..767 -> out += Wr@g + br
__global__ __launch_bounds__(256) void skipres_kernel(
    const float* __restrict__ g,
    const float* __restrict__ Wsk,   // [256][512]
    const float* __restrict__ Wr,    // [512][512]
    const float* __restrict__ bsk, const float* __restrict__ br,
    float* __restrict__ skip,        // [256][T]
    float* __restrict__ outp)        // [512][T]
{
    __shared__ float A[16][68];
    __shared__ float B[16][68];

    const int tid  = threadIdx.x;
    const int m0   = blockIdx.x * 64;   // 0..704
    const int t0   = blockIdx.y * 64;
    const int tc   = tid & 15, tr = tid >> 4;
    const int col0 = tc * 4,  row0 = tr * 4;
    const int mA  = tid >> 2;
    const int kA  = (tid & 3) * 4;
    const int ttB = tid & 63;
    const int kB0 = tid >> 6;

    float acc[4][4] = {{0.f}};

    const int mrow = m0 + mA;
    const float* wrow = (mrow < SCH) ? (Wsk + (size_t)mrow * RCH)
                                     : (Wr + (size_t)(mrow - SCH) * RCH);

    for (int kb = 0; kb < RCH; kb += 16) {
        {
            float4 w = *(const float4*)(wrow + kb + kA);
            A[kA + 0][mA] = w.x;
            A[kA + 1][mA] = w.y;
            A[kA + 2][mA] = w.z;
            A[kA + 3][mA] = w.w;
        }
        #pragma unroll
        for (int j = 0; j < 4; ++j) {
            int k = kB0 + j * 4;
            B[k][ttB] = g[(size_t)(kb + k) * T_LEN + t0 + ttB];
        }
        __syncthreads();
        #pragma unroll
        for (int kk = 0; kk < 16; ++kk) {
            float av[4], bv[4];
            *(float4*)av = *(const float4*)&A[kk][row0];
            *(float4*)bv = *(const float4*)&B[kk][col0];
            #pragma unroll
            for (int i = 0; i < 4; ++i)
                #pragma unroll
                for (int j = 0; j < 4; ++j)
                    acc[i][j] += av[i] * bv[j];
        }
        __syncthreads();
    }

    #pragma unroll
    for (int i = 0; i < 4; ++i) {
        int m = m0 + row0 + i;
        if (m < SCH) {
            float b = bsk[m];
            float* dst = &skip[(size_t)m * T_LEN + t0 + col0];
            float4 old = *(float4*)dst;
            old.x += acc[i][0] + b;
            old.y += acc[i][1] + b;
            old.z += acc[i][2] + b;
            old.w += acc[i][3] + b;
            *(float4*)dst = old;
        } else {
            float b = br[m - SCH];
            float* dst = &outp[(size_t)(m - SCH) * T_LEN + t0 + col0];
            float4 old = *(float4*)dst;
            old.x += acc[i][0] + b;
            old.y += acc[i][1] + b;
            old.z += acc[i][2] + b;
            old.w += acc[i][3] + b;
            *(float4*)dst = old;
        }
    }
}

// ---------------------------------------------------------------------------
// post1: o1 = relu(Wp1 @ relu(skip) + bp1)   M=256 K=256 N=T
__global__ __launch_bounds__(256) void post1_kernel(
    const float* __restrict__ skip, const float* __restrict__ Wp1,
    const float* __restrict__ bp1, float* __restrict__ o1)
{
    __shared__ float A[16][68];
    __shared__ float B[16][68];
    const int tid  = threadIdx.x;
    const int m0   = blockIdx.x * 64;
    const int t0   = blockIdx.y * 64;
    const int tc   = tid & 15, tr = tid >> 4;
    const int col0 = tc * 4,  row0 = tr * 4;
    const int mA  = tid >> 2;
    const int kA  = (tid & 3) * 4;
    const int ttB = tid & 63;
    const int kB0 = tid >> 6;

    float acc[4][4] = {{0.f}};

    for (int kb = 0; kb < SCH; kb += 16) {
        {
            float4 w = *(const float4*)(Wp1 + (size_t)(m0 + mA) * SCH + kb + kA);
            A[kA + 0][mA] = w.x; A[kA + 1][mA] = w.y;
            A[kA + 2][mA] = w.z; A[kA + 3][mA] = w.w;
        }
        #pragma unroll
        for (int j = 0; j < 4; ++j) {
            int k = kB0 + j * 4;
            B[k][ttB] = fmaxf(skip[(size_t)(kb + k) * T_LEN + t0 + ttB], 0.f);
        }
        __syncthreads();
        #pragma unroll
        for (int kk = 0; kk < 16; ++kk) {
            float av[4], bv[4];
            *(float4*)av = *(const float4*)&A[kk][row0];
            *(float4*)bv = *(const float4*)&B[kk][col0];
            #pragma unroll
            for (int i = 0; i < 4; ++i)
                #pragma unroll
                for (int j = 0; j < 4; ++j)
                    acc[i][j] += av[i] * bv[j];
        }
        __syncthreads();
    }
    #pragma unroll
    for (int i = 0; i < 4; ++i) {
        int m = m0 + row0 + i;
        float b = bp1[m];
        float4 v;
        v.x = fmaxf(acc[i][0] + b, 0.f);
        v.y = fmaxf(acc[i][1] + b, 0.f);
        v.z = fmaxf(acc[i][2] + b, 0.f);
        v.w = fmaxf(acc[i][3] + b, 0.f);
        *(float4*)&o1[(size_t)m * T_LEN + t0 + col0] = v;
    }
}

// post2: d_out[t][q] = Wp2 @ o1 + bp2  (transposed write)
__global__ __launch_bounds__(256) void post2_kernel(
    const float* __restrict__ o1, const float* __restrict__ Wp2,
    const float* __restrict__ bp2, float* __restrict__ dout)
{
    __shared__ float A[16][68];
    __shared__ float B[16][68];
    const int tid  = threadIdx.x;
    const int m0   = blockIdx.x * 64;   // q block
    const int t0   = blockIdx.y * 64;
    const int tc   = tid & 15, tr = tid >> 4;
    const int col0 = tc * 4,  row0 = tr * 4;
    const int mA  = tid >> 2;
    const int kA  = (tid & 3) * 4;
    const int ttB = tid & 63;
    const int kB0 = tid >> 6;

    float acc[4][4] = {{0.f}};

    for (int kb = 0; kb < SCH; kb += 16) {
        {
            float4 w = *(const float4*)(Wp2 + (size_t)(m0 + mA) * SCH + kb + kA);
            A[kA + 0][mA] = w.x; A[kA + 1][mA] = w.y;
            A[kA + 2][mA] = w.z; A[kA + 3][mA] = w.w;
        }
        #pragma unroll
        for (int j = 0; j < 4; ++j) {
            int k = kB0 + j * 4;
            B[k][ttB] = o1[(size_t)(kb + k) * T_LEN + t0 + ttB];
        }
        __syncthreads();
        #pragma unroll
        for (int kk = 0; kk < 16; ++kk) {
            float av[4], bv[4];
            *(float4*)av = *(const float4*)&A[kk][row0];
            *(float4*)bv = *(const float4*)&B[kk][col0];
            #pragma unroll
            for (int i = 0; i < 4; ++i)
                #pragma unroll
                for (int j = 0; j < 4; ++j)
                    acc[i][j] += av[i] * bv[j];
        }
        __syncthreads();
    }
    // transposed write: dout[(t0+col)*QCH + q], 4 consecutive q per store
    #pragma unroll
    for (int j = 0; j < 4; ++j) {
        int t = t0 + col0 + j;
        float4 v;
        v.x = acc[0][j] + bp2[m0 + row0 + 0];
        v.y = acc[1][j] + bp2[m0 + row0 + 1];
        v.z = acc[2][j] + bp2[m0 + row0 + 2];
        v.w = acc[3][j] + bp2[m0 + row0 + 3];
        *(float4*)&dout[(size_t)t * QCH + m0 + row0] = v;
    }
}

// ---------------------------------------------------------------------------
extern "C" void kernel_launch(void* const* d_in, const int* in_sizes, int n_in,
                              void* d_out, int out_size, void* d_ws, size_t ws_size,
                              hipStream_t stream) {
    const int*   x   = (const int*)  d_in[0];
    const float* h   = (const float*)d_in[1];
    const float* Wc  = (const float*)d_in[2];
    const float* bc  = (const float*)d_in[3];
    const float* Wds = (const float*)d_in[4];
    const float* bds = (const float*)d_in[5];
    const float* Wdt = (const float*)d_in[6];
    const float* bdt = (const float*)d_in[7];
    const float* Was = (const float*)d_in[8];
    const float* bas = (const float*)d_in[9];
    const float* Wat = (const float*)d_in[10];
    const float* bat = (const float*)d_in[11];
    const float* Wsk = (const float*)d_in[12];
    const float* bsk = (const float*)d_in[13];
    const float* Wr  = (const float*)d_in[14];
    const float* br  = (const float*)d_in[15];
    const float* Wp1 = (const float*)d_in[16];
    const float* bp1 = (const float*)d_in[17];
    const float* Wp2 = (const float*)d_in[18];
    const float* bp2 = (const float*)d_in[19];
    float* dout = (float*)d_out;

    float* ws     = (float*)d_ws;
    float* outbuf = ws;                                  // 512*8192 f32 = 16 MB
    float* gbuf   = ws + (size_t)RCH * T_LEN;            // 16 MB
    float* o1buf  = ws + (size_t)2 * RCH * T_LEN;        // 8 MB
    float* skip   = dout;                                // 256*8192 f32 = d_out, reused as accumulator

    // zero the skip accumulator (d_out) — 2M floats = 512K float4
    zero_kernel<<<2048, 256, 0, stream>>>((float4*)skip);

    embed_kernel<<<(RCH * T_LEN) / 256, 256, 0, stream>>>(x, Wc, bc, outbuf);

    for (int l = 0; l < NLAYER; ++l) {
        int d = 1 << (l % 10);
        gate_kernel<<<dim3(8, 128), 256, 0, stream>>>(
            outbuf, h,
            Wds + (size_t)l * RCH * RCH * 2,
            Wdt + (size_t)l * RCH * RCH * 2,
            Was + (size_t)l * RCH * ACH,
            Wat + (size_t)l * RCH * ACH,
            bds + (size_t)l * RCH, bdt + (size_t)l * RCH,
            bas + (size_t)l * RCH, bat + (size_t)l * RCH,
            gbuf, d);
        skipres_kernel<<<dim3(12, 128), 256, 0, stream>>>(
            gbuf,
            Wsk + (size_t)l * SCH * RCH,
            Wr  + (size_t)l * RCH * RCH,
            bsk + (size_t)l * SCH,
            br  + (size_t)l * RCH,
            skip, outbuf);
    }

    post1_kernel<<<dim3(4, 128), 256, 0, stream>>>(skip, Wp1, bp1, o1buf);
    post2_kernel<<<dim3(4, 128), 256, 0, stream>>>(o1buf, Wp2, bp2, dout);
}

// Round 3
// 1986.077 us; speedup vs baseline: 11.1520x; 11.1520x over previous
//
#include <hip/hip_runtime.h>
#include <hip/hip_bf16.h>
#include <math.h>
#include <stdint.h>

#define T_LEN 8192
#define RCH   512
#define SCH   256
#define QCH   256
#define ACH   28
#define NLAYER 30
#define KGATE 1056   // 512 tap0 + 512 tap1 + 32 aux (zero-padded from 28)
#define KSR   512
#define KPOST 256

typedef _Float16 f16x8 __attribute__((ext_vector_type(8)));
typedef float    f32x4 __attribute__((ext_vector_type(4)));

static __device__ __forceinline__ unsigned short f2h(float v) {
    _Float16 h = (_Float16)v;                 // RTN
    return *reinterpret_cast<unsigned short*>(&h);
}

// global -> LDS direct copy, 16B per lane, LDS dest wave-uniform base
#define G2L(SRC, DST) __builtin_amdgcn_global_load_lds(                        \
    (__attribute__((address_space(1))) void*)(const void*)(SRC),              \
    (__attribute__((address_space(3))) void*)(void*)(DST), 16, 0, 0)

// ---------------------------------------------------------------------------
// Weight packing into MFMA fragment order (fp16).
// packed[(mtile*KT + ktile)*512 + lane*8 + i] = A[mtile*16 + (lane&15)][ktile*32 + (lane>>4)*8 + i]
// Gate A rows interleaved: row 2r = s-branch channel r (Wds/Was), row 2r+1 = t-branch (Wdt/Wat).
// k<512: tap0 (multiplies out[t-dil]); 512<=k<1024: tap1 (out[t]); k>=1024: aux (h), zero-pad 28..31.
__global__ void pack_gate_kernel(const float* __restrict__ Wds,
                                 const float* __restrict__ Wdt,
                                 const float* __restrict__ Was,
                                 const float* __restrict__ Wat,
                                 unsigned short* __restrict__ dst) {
    int e = blockIdx.x * 256 + threadIdx.x;           // exact grid: 1024*1056/256
    int tile = e >> 9;
    int r9 = e & 511;
    int lane = r9 >> 3, i = r9 & 7;
    int mt = tile / (KGATE / 32), kt = tile % (KGATE / 32);
    int m = mt * 16 + (lane & 15);
    int k = kt * 32 + (lane >> 4) * 8 + i;
    int br = m & 1, ch = m >> 1;
    float v;
    if (k < 512) {
        const float* W = br ? Wdt : Wds;
        v = W[((size_t)ch * 512 + k) * 2 + 0];
    } else if (k < 1024) {
        const float* W = br ? Wdt : Wds;
        v = W[((size_t)ch * 512 + (k - 512)) * 2 + 1];
    } else {
        int a = k - 1024;
        const float* W = br ? Wat : Was;
        v = (a < ACH) ? W[(size_t)ch * ACH + a] : 0.f;
    }
    dst[e] = f2h(v);
}

__global__ void pack_sr_kernel(const float* __restrict__ Wsk,
                               const float* __restrict__ Wr,
                               unsigned short* __restrict__ dst) {
    int e = blockIdx.x * 256 + threadIdx.x;           // 768*512/256
    int tile = e >> 9;
    int r9 = e & 511;
    int lane = r9 >> 3, i = r9 & 7;
    int mt = tile / (KSR / 32), kt = tile % (KSR / 32);
    int m = mt * 16 + (lane & 15);
    int k = kt * 32 + (lane >> 4) * 8 + i;
    float v = (m < SCH) ? Wsk[(size_t)m * 512 + k]
                        : Wr[(size_t)(m - SCH) * 512 + k];
    dst[e] = f2h(v);
}

__global__ void pack_post_kernel(const float* __restrict__ W,
                                 unsigned short* __restrict__ dst) {
    int e = blockIdx.x * 256 + threadIdx.x;           // 256*256/256
    int tile = e >> 9;
    int r9 = e & 511;
    int lane = r9 >> 3, i = r9 & 7;
    int mt = tile / (KPOST / 32), kt = tile % (KPOST / 32);
    int m = mt * 16 + (lane & 15);
    int k = kt * 32 + (lane >> 4) * 8 + i;
    dst[e] = f2h(W[(size_t)m * 256 + k]);
}

// ---------------------------------------------------------------------------
// embed: out_tm[t][r] (f32) and outhf[512+t][r] (fp16), time-major.
__global__ void embed_kernel2(const int* __restrict__ x,
                              const float* __restrict__ Wc,
                              const float* __restrict__ bc,
                              float* __restrict__ out_tm,
                              unsigned short* __restrict__ outhf) {
    int idx = blockIdx.x * 256 + threadIdx.x;         // 8192*512/256
    int t = idx >> 9, r = idx & 511;
    float v = Wc[((size_t)r * QCH + x[t]) * 2 + 1] + bc[r];
    if (t > 0) v += Wc[((size_t)r * QCH + x[t - 1]) * 2 + 0];
    out_tm[idx] = v;
    outhf[(size_t)idx + 512 * 512] = f2h(v);
}

// h -> time-major fp16 [8192][32], zero-padded channels 28..31
__global__ void packh_kernel(const float* __restrict__ h,
                             unsigned short* __restrict__ h_tm) {
    int idx = blockIdx.x * 256 + threadIdx.x;         // 8192*32/256
    int t = idx >> 5, a = idx & 31;
    h_tm[idx] = f2h(a < ACH ? h[(size_t)a * T_LEN + t] : 0.f);
}

// relu(skip) -> fp16
__global__ void reluconv_kernel(const float* __restrict__ skip,
                                unsigned short* __restrict__ dst) {
    int idx = blockIdx.x * 256 + threadIdx.x;         // 8192*256/256
    dst[idx] = f2h(fmaxf(skip[idx], 0.f));
}

// ---------------------------------------------------------------------------
// MFMA GEMM, tile 128(M) x 64(N=time), BK=32, 4 waves (256 thr).
// A pre-packed fragment-order fp16 (global->reg). B^T time-major fp16 via
// global_load_lds into [64][32] LDS. C = fp32 frags; mode-specific epilogue.
// MODE 0: gate (B regions: outhf shifted / outhf / h_tm; epi: sigmoid*tanh -> g_tm fp16)
// MODE 1: skipres (epi: skip += / out_tm += ; outhf = fp16(out))
// MODE 2: post1 (epi: relu -> o1hf)
// MODE 3: post2 (epi: dout[t][q] f32)
template<int MODE, int KT>
__global__ __launch_bounds__(256) void mfma_gemm(
    const unsigned short* __restrict__ Apk,
    const unsigned short* __restrict__ B0,
    const unsigned short* __restrict__ B2,
    const float* __restrict__ bias0, const float* __restrict__ bias1,
    const float* __restrict__ bias2, const float* __restrict__ bias3,
    float* __restrict__ O0, float* __restrict__ O1,
    unsigned short* __restrict__ OB, int dil)
{
    __shared__ unsigned short Bsm[64 * 32];

    const int tid  = threadIdx.x;
    const int lane = tid & 63, wave = tid >> 6;
    const int wm = wave & 1, wn = wave >> 1;
    const int m0 = blockIdx.x * 128;
    const int t0 = blockIdx.y * 64;

    // B staging map: wave covers 16 t-rows, lane -> (row, 16B chunk)
    const int srow = wave * 16 + (lane >> 2);
    const int skw  = (lane & 3) * 8;
    const int tg   = t0 + srow;

    f32x4 acc[4][2];
    #pragma unroll
    for (int a = 0; a < 4; ++a)
        #pragma unroll
        for (int b = 0; b < 2; ++b) acc[a][b] = (f32x4){0.f, 0.f, 0.f, 0.f};

    const size_t mt0 = (size_t)(m0 >> 4) + wm * 4;

    for (int kt = 0; kt < KT; ++kt) {
        // ---- stage B tile ----
        const unsigned short* src;
        if constexpr (MODE == 0) {
            int kb = kt * 32;
            if (kb < 512)
                src = B0 + (size_t)(512 + tg - dil) * 512 + kb + skw;
            else if (kb < 1024)
                src = B0 + (size_t)(512 + tg) * 512 + (kb - 512) + skw;
            else
                src = B2 + (size_t)tg * 32 + (kb - 1024) + skw;
        } else if constexpr (MODE == 1) {
            src = B0 + (size_t)tg * 512 + kt * 32 + skw;
        } else {
            src = B0 + (size_t)tg * 256 + kt * 32 + skw;
        }
        G2L(src, &Bsm[wave * 512]);

        // ---- A fragments (packed, from L2) ----
        f16x8 afr[4];
        #pragma unroll
        for (int mi = 0; mi < 4; ++mi)
            afr[mi] = *(const f16x8*)(Apk + ((mt0 + mi) * KT + kt) * 512 + lane * 8);

        __syncthreads();

        f16x8 bfr[2];
        #pragma unroll
        for (int ni = 0; ni < 2; ++ni)
            bfr[ni] = *(const f16x8*)&Bsm[(wn * 32 + ni * 16 + (lane & 15)) * 32 + (lane >> 4) * 8];

        #pragma unroll
        for (int mi = 0; mi < 4; ++mi)
            #pragma unroll
            for (int ni = 0; ni < 2; ++ni)
                acc[mi][ni] = __builtin_amdgcn_mfma_f32_16x16x32_f16(
                    afr[mi], bfr[ni], acc[mi][ni], 0, 0, 0);

        __syncthreads();
    }

    // ---- epilogue ----
    const int rb0 = (lane >> 4) * 4;
    #pragma unroll
    for (int mi = 0; mi < 4; ++mi) {
        #pragma unroll
        for (int ni = 0; ni < 2; ++ni) {
            int m = m0 + wm * 64 + mi * 16 + rb0;     // multiple of 4
            int t = t0 + wn * 32 + ni * 16 + (lane & 15);
            f32x4 v = acc[mi][ni];
            if constexpr (MODE == 0) {
                int c0 = m >> 1;                       // even
                float s0 = v.x + bias0[c0]     + bias2[c0];
                float tv0 = v.y + bias1[c0]     + bias3[c0];
                float s1 = v.z + bias0[c0 + 1] + bias2[c0 + 1];
                float tv1 = v.w + bias1[c0 + 1] + bias3[c0 + 1];
                float g0 = (1.f / (1.f + __expf(-s0))) * tanhf(tv0);
                float g1 = (1.f / (1.f + __expf(-s1))) * tanhf(tv1);
                unsigned int p = (unsigned int)f2h(g0) | ((unsigned int)f2h(g1) << 16);
                *(unsigned int*)&OB[(size_t)t * 512 + c0] = p;
            } else if constexpr (MODE == 1) {
                if (m < SCH) {
                    float4* p = (float4*)&O0[(size_t)t * 256 + m];
                    float4 o = *p;
                    o.x += v.x + bias0[m + 0];
                    o.y += v.y + bias0[m + 1];
                    o.z += v.z + bias0[m + 2];
                    o.w += v.w + bias0[m + 3];
                    *p = o;
                } else {
                    int c = m - SCH;
                    float4* p = (float4*)&O1[(size_t)t * 512 + c];
                    float4 o = *p;
                    o.x += v.x + bias1[c + 0];
                    o.y += v.y + bias1[c + 1];
                    o.z += v.z + bias1[c + 2];
                    o.w += v.w + bias1[c + 3];
                    *p = o;
                    uint2 pk;
                    pk.x = (unsigned int)f2h(o.x) | ((unsigned int)f2h(o.y) << 16);
                    pk.y = (unsigned int)f2h(o.z) | ((unsigned int)f2h(o.w) << 16);
                    *(uint2*)&OB[(size_t)(512 + t) * 512 + c] = pk;
                }
            } else if constexpr (MODE == 2) {
                float o0 = fmaxf(v.x + bias0[m + 0], 0.f);
                float o1 = fmaxf(v.y + bias0[m + 1], 0.f);
                float o2 = fmaxf(v.z + bias0[m + 2], 0.f);
                float o3 = fmaxf(v.w + bias0[m + 3], 0.f);
                uint2 pk;
                pk.x = (unsigned int)f2h(o0) | ((unsigned int)f2h(o1) << 16);
                pk.y = (unsigned int)f2h(o2) | ((unsigned int)f2h(o3) << 16);
                *(uint2*)&OB[(size_t)t * 256 + m] = pk;
            } else {
                float4 o;
                o.x = v.x + bias0[m + 0];
                o.y = v.y + bias0[m + 1];
                o.z = v.z + bias0[m + 2];
                o.w = v.w + bias0[m + 3];
                *(float4*)&O0[(size_t)t * 256 + m] = o;
            }
        }
    }
}

// ---------------------------------------------------------------------------
extern "C" void kernel_launch(void* const* d_in, const int* in_sizes, int n_in,
                              void* d_out, int out_size, void* d_ws, size_t ws_size,
                              hipStream_t stream) {
    const int*   x   = (const int*)  d_in[0];
    const float* h   = (const float*)d_in[1];
    const float* Wc  = (const float*)d_in[2];
    const float* bc  = (const float*)d_in[3];
    const float* Wds = (const float*)d_in[4];
    const float* bds = (const float*)d_in[5];
    const float* Wdt = (const float*)d_in[6];
    const float* bdt = (const float*)d_in[7];
    const float* Was = (const float*)d_in[8];
    const float* bas = (const float*)d_in[9];
    const float* Wat = (const float*)d_in[10];
    const float* bat = (const float*)d_in[11];
    const float* Wsk = (const float*)d_in[12];
    const float* bsk = (const float*)d_in[13];
    const float* Wr  = (const float*)d_in[14];
    const float* br  = (const float*)d_in[15];
    const float* Wp1 = (const float*)d_in[16];
    const float* bp1 = (const float*)d_in[17];
    const float* Wp2 = (const float*)d_in[18];
    const float* bp2 = (const float*)d_in[19];
    float* dout = (float*)d_out;

    // ---- workspace layout (bytes) ----
    char* w = (char*)d_ws;
    float*          out_tm = (float*)w;                 w += (size_t)T_LEN * 512 * 4;        // 16 MB
    unsigned short* outhf  = (unsigned short*)w;        w += (size_t)(T_LEN + 512) * 512 * 2; // 8.9 MB (512-row zero prefix)
    unsigned short* g_tm   = (unsigned short*)w;        w += (size_t)T_LEN * 512 * 2;        // 8 MB
    unsigned short* h_tm   = (unsigned short*)w;        w += (size_t)T_LEN * 32 * 2;         // 0.5 MB
    unsigned short* skiphf = (unsigned short*)w;        w += (size_t)T_LEN * 256 * 2;        // 4 MB
    unsigned short* o1hf   = (unsigned short*)w;        w += (size_t)T_LEN * 256 * 2;        // 4 MB
    unsigned short* Wg_pk  = (unsigned short*)w;        w += (size_t)1024 * KGATE * 2;       // 2.2 MB
    unsigned short* Wsr_pk = (unsigned short*)w;        w += (size_t)768 * KSR * 2;          // 0.8 MB
    unsigned short* Wp1_pk = (unsigned short*)w;        w += (size_t)256 * 256 * 2;
    unsigned short* Wp2_pk = (unsigned short*)w;        w += (size_t)256 * 256 * 2;
    float* skip = dout;                                  // [8192][256] f32 accumulator in d_out

    // per-call init: skip accumulator = 0, outhf zero prefix = 0
    hipMemsetAsync(skip, 0, (size_t)T_LEN * 256 * 4, stream);
    hipMemsetAsync(outhf, 0, (size_t)512 * 512 * 2, stream);

    embed_kernel2<<<(T_LEN * 512) / 256, 256, 0, stream>>>(x, Wc, bc, out_tm, outhf);
    packh_kernel<<<(T_LEN * 32) / 256, 256, 0, stream>>>(h, h_tm);
    pack_post_kernel<<<256, 256, 0, stream>>>(Wp1, Wp1_pk);
    pack_post_kernel<<<256, 256, 0, stream>>>(Wp2, Wp2_pk);

    for (int l = 0; l < NLAYER; ++l) {
        int dil = 1 << (l % 10);
        pack_gate_kernel<<<(1024 * KGATE) / 256, 256, 0, stream>>>(
            Wds + (size_t)l * RCH * RCH * 2,
            Wdt + (size_t)l * RCH * RCH * 2,
            Was + (size_t)l * RCH * ACH,
            Wat + (size_t)l * RCH * ACH, Wg_pk);
        mfma_gemm<0, KGATE / 32><<<dim3(8, 128), 256, 0, stream>>>(
            Wg_pk, outhf, h_tm,
            bds + (size_t)l * RCH, bdt + (size_t)l * RCH,
            bas + (size_t)l * RCH, bat + (size_t)l * RCH,
            nullptr, nullptr, g_tm, dil);
        pack_sr_kernel<<<(768 * KSR) / 256, 256, 0, stream>>>(
            Wsk + (size_t)l * SCH * RCH,
            Wr  + (size_t)l * RCH * RCH, Wsr_pk);
        mfma_gemm<1, KSR / 32><<<dim3(6, 128), 256, 0, stream>>>(
            Wsr_pk, g_tm, nullptr,
            bsk + (size_t)l * SCH, br + (size_t)l * RCH, nullptr, nullptr,
            skip, out_tm, outhf, 0);
    }

    reluconv_kernel<<<(T_LEN * 256) / 256, 256, 0, stream>>>(skip, skiphf);
    mfma_gemm<2, KPOST / 32><<<dim3(2, 128), 256, 0, stream>>>(
        Wp1_pk, skiphf, nullptr, bp1, nullptr, nullptr, nullptr,
        nullptr, nullptr, o1hf, 0);
    mfma_gemm<3, KPOST / 32><<<dim3(2, 128), 256, 0, stream>>>(
        Wp2_pk, o1hf, nullptr, bp2, nullptr, nullptr, nullptr,
        dout, nullptr, nullptr, 0);
}

// Round 4
// 1711.471 us; speedup vs baseline: 12.9413x; 1.1605x over previous
//
#include <hip/hip_runtime.h>
#include <hip/hip_bf16.h>
#include <math.h>
#include <stdint.h>

#define T_LEN 8192
#define RCH   512
#define SCH   256
#define QCH   256
#define ACH   28
#define NLAYER 30
#define KGATE 1088   // 512 tap0 + 512 tap1 + 64 aux (zero-padded from 28) = 17*64
#define KSR   512
#define KPOST 256

typedef _Float16 f16x8 __attribute__((ext_vector_type(8)));
typedef float    f32x4 __attribute__((ext_vector_type(4)));

static __device__ __forceinline__ unsigned short f2h(float v) {
    _Float16 h = (_Float16)v;                 // RTN
    return *reinterpret_cast<unsigned short*>(&h);
}

// global -> LDS direct copy, 16B per lane, LDS dest wave-uniform base
#define G2L(SRC, DST) __builtin_amdgcn_global_load_lds(                        \
    (__attribute__((address_space(1))) void*)(const void*)(SRC),              \
    (__attribute__((address_space(3))) void*)(void*)(DST), 16, 0, 0)

// ---------------------------------------------------------------------------
// Weight packing into MFMA fragment order (fp16).
// packed[l][(mt*KT32 + kt)*512 + lane*8 + i] = A[mt*16 + (lane&15)][kt*32 + (lane>>4)*8 + i]
// Gate A rows interleaved: row 2r = s-branch channel r (Wds/Was), row 2r+1 = t-branch.
// k<512: tap0 (out[t-dil]); 512<=k<1024: tap1 (out[t]); k>=1024: aux (h), zero-pad 28..63.
__global__ void pack_gate_kernel(const float* __restrict__ Wds,
                                 const float* __restrict__ Wdt,
                                 const float* __restrict__ Was,
                                 const float* __restrict__ Wat,
                                 unsigned short* __restrict__ dst) {
    int l = blockIdx.y;
    int e = blockIdx.x * 256 + threadIdx.x;           // grid.x = 1024*1088/256 = 4352
    int tile = e >> 9;
    int r9 = e & 511;
    int lane = r9 >> 3, i = r9 & 7;
    int mt = tile / 34, kt = tile % 34;               // KT32 = 34
    int m = mt * 16 + (lane & 15);
    int k = kt * 32 + (lane >> 4) * 8 + i;
    int br = m & 1, ch = m >> 1;
    const float* Wd = (br ? Wdt : Wds) + (size_t)l * RCH * RCH * 2;
    const float* Wa = (br ? Wat : Was) + (size_t)l * RCH * ACH;
    float v;
    if (k < 512)       v = Wd[((size_t)ch * 512 + k) * 2 + 0];
    else if (k < 1024) v = Wd[((size_t)ch * 512 + (k - 512)) * 2 + 1];
    else { int a = k - 1024; v = (a < ACH) ? Wa[(size_t)ch * ACH + a] : 0.f; }
    dst[(size_t)l * 1024 * KGATE + e] = f2h(v);
}

__global__ void pack_sr_kernel(const float* __restrict__ Wsk,
                               const float* __restrict__ Wr,
                               unsigned short* __restrict__ dst) {
    int l = blockIdx.y;
    int e = blockIdx.x * 256 + threadIdx.x;           // grid.x = 768*512/256 = 1536
    int tile = e >> 9;
    int r9 = e & 511;
    int lane = r9 >> 3, i = r9 & 7;
    int mt = tile >> 4, kt = tile & 15;               // KT32 = 16
    int m = mt * 16 + (lane & 15);
    int k = kt * 32 + (lane >> 4) * 8 + i;
    float v = (m < SCH) ? Wsk[(size_t)l * SCH * RCH + (size_t)m * 512 + k]
                        : Wr[(size_t)l * RCH * RCH + (size_t)(m - SCH) * 512 + k];
    dst[(size_t)l * 768 * KSR + e] = f2h(v);
}

__global__ void pack_post_kernel(const float* __restrict__ W,
                                 unsigned short* __restrict__ dst) {
    int e = blockIdx.x * 256 + threadIdx.x;           // 256*256/256 = 256
    int tile = e >> 9;
    int r9 = e & 511;
    int lane = r9 >> 3, i = r9 & 7;
    int mt = tile >> 3, kt = tile & 7;                // KT32 = 8
    int m = mt * 16 + (lane & 15);
    int k = kt * 32 + (lane >> 4) * 8 + i;
    dst[e] = f2h(W[(size_t)m * 256 + k]);
}

// ---------------------------------------------------------------------------
// embed: out_tm[t][r] (f32) and outhf[512+t][r] (fp16), time-major.
__global__ void embed_kernel2(const int* __restrict__ x,
                              const float* __restrict__ Wc,
                              const float* __restrict__ bc,
                              float* __restrict__ out_tm,
                              unsigned short* __restrict__ outhf) {
    int idx = blockIdx.x * 256 + threadIdx.x;         // 8192*512/256
    int t = idx >> 9, r = idx & 511;
    float v = Wc[((size_t)r * QCH + x[t]) * 2 + 1] + bc[r];
    if (t > 0) v += Wc[((size_t)r * QCH + x[t - 1]) * 2 + 0];
    out_tm[idx] = v;
    outhf[(size_t)idx + 512 * 512] = f2h(v);
}

// h -> time-major fp16 [8192][64], zero-padded channels 28..63
__global__ void packh_kernel(const float* __restrict__ h,
                             unsigned short* __restrict__ h_tm) {
    int idx = blockIdx.x * 256 + threadIdx.x;         // 8192*64/256
    int t = idx >> 6, a = idx & 63;
    h_tm[idx] = f2h(a < ACH ? h[(size_t)a * T_LEN + t] : 0.f);
}

// relu(skip) -> fp16
__global__ void reluconv_kernel(const float* __restrict__ skip,
                                unsigned short* __restrict__ dst) {
    int idx = blockIdx.x * 256 + threadIdx.x;         // 8192*256/256
    dst[idx] = f2h(fmaxf(skip[idx], 0.f));
}

// ---------------------------------------------------------------------------
// MFMA GEMM, tile 128(M) x 128(N=time), BK=64, 4 waves (256 thr).
// A pre-packed fragment-order fp16 (global->reg, L2-hot). B^T time-major fp16
// staged via global_load_lds into [128 rows][8 chunks of 16B] LDS with XOR
// swizzle (chunk ^= row&7) applied on the pre-swizzled GLOBAL source and on
// the ds_read address (both-sides rule). C = fp32 frags; per-MODE epilogue.
// Grid: flat NWG = MB*64 blocks, bijective XCD swizzle (NWG%8==0), mb fastest.
// MODE 0: gate -> g_tm fp16;  MODE 1: skipres (skip+=, out+=, outhf=fp16);
// MODE 2: post1 relu -> OB;   MODE 3: post2 -> dout f32.
template<int MODE, int KT64, int MB>
__global__ __launch_bounds__(256) void mfma_gemm(
    const unsigned short* __restrict__ Apk,
    const unsigned short* __restrict__ B0,
    const unsigned short* __restrict__ B2,
    const float* __restrict__ bias0, const float* __restrict__ bias1,
    const float* __restrict__ bias2, const float* __restrict__ bias3,
    float* __restrict__ O0, float* __restrict__ O1,
    unsigned short* __restrict__ OB, int dil)
{
    constexpr int KT32 = KT64 * 2;
    constexpr int NWG = MB * 64;
    constexpr int CPX = NWG / 8;

    __shared__ unsigned short Bsm[128 * 64];          // 16 KB

    const int tid  = threadIdx.x;
    const int lane = tid & 63, wave = tid >> 6;
    const int wm = wave & 1, wn = wave >> 1;

    const int bid = blockIdx.x;
    const int swz = (bid & 7) * CPX + (bid >> 3);     // bijective XCD swizzle
    const int mb  = swz % MB;
    const int tb  = swz / MB;
    const int m0  = mb * 128;
    const int t0  = tb * 128;

    // staging: G2L j stages rows wave*32+j*8 .. +8; lane -> (row=lane>>3, chunk=lane&7)
    // LDS[row][sc] holds content chunk sc ^ (row&7); row&7 == lane>>3 here.
    const int kc   = ((lane & 7) ^ (lane >> 3)) * 8;  // element offset of content chunk
    const int rsub = lane >> 3;                       // row within 8-row group

    f32x4 acc[4][4];
    #pragma unroll
    for (int a = 0; a < 4; ++a)
        #pragma unroll
        for (int b = 0; b < 4; ++b) acc[a][b] = (f32x4){0.f, 0.f, 0.f, 0.f};

    const size_t mt0 = (size_t)(mb * 8) + wm * 4;

    for (int kt = 0; kt < KT64; ++kt) {
        const int kb = kt * 64;
        // ---- stage B tile (pre-swizzled source) ----
        #pragma unroll
        for (int j = 0; j < 4; ++j) {
            const int row = wave * 32 + j * 8 + rsub;
            const int tg  = t0 + row;
            const unsigned short* src;
            if constexpr (MODE == 0) {
                if (kb < 512)
                    src = B0 + (size_t)(512 + tg - dil) * 512 + kb + kc;
                else if (kb < 1024)
                    src = B0 + (size_t)(512 + tg) * 512 + (kb - 512) + kc;
                else
                    src = B2 + (size_t)tg * 64 + kc;
            } else if constexpr (MODE == 1) {
                src = B0 + (size_t)tg * 512 + kb + kc;
            } else {
                src = B0 + (size_t)tg * 256 + kb + kc;
            }
            G2L(src, &Bsm[(wave * 4 + j) * 512]);
        }

        // ---- A fragments (packed, from L2) ----
        f16x8 afr[4][2];
        #pragma unroll
        for (int mi = 0; mi < 4; ++mi)
            #pragma unroll
            for (int ks = 0; ks < 2; ++ks)
                afr[mi][ks] = *(const f16x8*)(Apk +
                    ((mt0 + mi) * KT32 + (size_t)(kt * 2 + ks)) * 512 + lane * 8);

        __syncthreads();

        // ---- B fragments from LDS (swizzled read) ----
        f16x8 bfr[4][2];
        #pragma unroll
        for (int ni = 0; ni < 4; ++ni)
            #pragma unroll
            for (int ks = 0; ks < 2; ++ks) {
                const int trow = wn * 64 + ni * 16 + (lane & 15);
                const int kch  = ks * 4 + (lane >> 4);
                const int sch  = kch ^ (lane & 7);    // trow&7 == lane&7
                bfr[ni][ks] = *(const f16x8*)&Bsm[trow * 64 + sch * 8];
            }

        #pragma unroll
        for (int mi = 0; mi < 4; ++mi)
            #pragma unroll
            for (int ni = 0; ni < 4; ++ni) {
                acc[mi][ni] = __builtin_amdgcn_mfma_f32_16x16x32_f16(
                    afr[mi][0], bfr[ni][0], acc[mi][ni], 0, 0, 0);
                acc[mi][ni] = __builtin_amdgcn_mfma_f32_16x16x32_f16(
                    afr[mi][1], bfr[ni][1], acc[mi][ni], 0, 0, 0);
            }

        __syncthreads();
    }

    // ---- epilogue ----
    const int rb0 = (lane >> 4) * 4;
    #pragma unroll
    for (int mi = 0; mi < 4; ++mi) {
        #pragma unroll
        for (int ni = 0; ni < 4; ++ni) {
            int m = m0 + wm * 64 + mi * 16 + rb0;     // multiple of 4
            int t = t0 + wn * 64 + ni * 16 + (lane & 15);
            f32x4 v = acc[mi][ni];
            if constexpr (MODE == 0) {
                int c0 = m >> 1;                       // even
                float s0 = v.x + bias0[c0]     + bias2[c0];
                float tv0 = v.y + bias1[c0]     + bias3[c0];
                float s1 = v.z + bias0[c0 + 1] + bias2[c0 + 1];
                float tv1 = v.w + bias1[c0 + 1] + bias3[c0 + 1];
                float g0 = (1.f / (1.f + __expf(-s0))) * tanhf(tv0);
                float g1 = (1.f / (1.f + __expf(-s1))) * tanhf(tv1);
                unsigned int p = (unsigned int)f2h(g0) | ((unsigned int)f2h(g1) << 16);
                *(unsigned int*)&OB[(size_t)t * 512 + c0] = p;
            } else if constexpr (MODE == 1) {
                if (m < SCH) {
                    float4* p = (float4*)&O0[(size_t)t * 256 + m];
                    float4 o = *p;
                    o.x += v.x + bias0[m + 0];
                    o.y += v.y + bias0[m + 1];
                    o.z += v.z + bias0[m + 2];
                    o.w += v.w + bias0[m + 3];
                    *p = o;
                } else {
                    int c = m - SCH;
                    float4* p = (float4*)&O1[(size_t)t * 512 + c];
                    float4 o = *p;
                    o.x += v.x + bias1[c + 0];
                    o.y += v.y + bias1[c + 1];
                    o.z += v.z + bias1[c + 2];
                    o.w += v.w + bias1[c + 3];
                    *p = o;
                    uint2 pk;
                    pk.x = (unsigned int)f2h(o.x) | ((unsigned int)f2h(o.y) << 16);
                    pk.y = (unsigned int)f2h(o.z) | ((unsigned int)f2h(o.w) << 16);
                    *(uint2*)&OB[(size_t)(512 + t) * 512 + c] = pk;
                }
            } else if constexpr (MODE == 2) {
                float o0 = fmaxf(v.x + bias0[m + 0], 0.f);
                float o1 = fmaxf(v.y + bias0[m + 1], 0.f);
                float o2 = fmaxf(v.z + bias0[m + 2], 0.f);
                float o3 = fmaxf(v.w + bias0[m + 3], 0.f);
                uint2 pk;
                pk.x = (unsigned int)f2h(o0) | ((unsigned int)f2h(o1) << 16);
                pk.y = (unsigned int)f2h(o2) | ((unsigned int)f2h(o3) << 16);
                *(uint2*)&OB[(size_t)t * 256 + m] = pk;
            } else {
                float4 o;
                o.x = v.x + bias0[m + 0];
                o.y = v.y + bias0[m + 1];
                o.z = v.z + bias0[m + 2];
                o.w = v.w + bias0[m + 3];
                *(float4*)&O0[(size_t)t * 256 + m] = o;
            }
        }
    }
}

// ---------------------------------------------------------------------------
extern "C" void kernel_launch(void* const* d_in, const int* in_sizes, int n_in,
                              void* d_out, int out_size, void* d_ws, size_t ws_size,
                              hipStream_t stream) {
    const int*   x   = (const int*)  d_in[0];
    const float* h   = (const float*)d_in[1];
    const float* Wc  = (const float*)d_in[2];
    const float* bc  = (const float*)d_in[3];
    const float* Wds = (const float*)d_in[4];
    const float* bds = (const float*)d_in[5];
    const float* Wdt = (const float*)d_in[6];
    const float* bdt = (const float*)d_in[7];
    const float* Was = (const float*)d_in[8];
    const float* bas = (const float*)d_in[9];
    const float* Wat = (const float*)d_in[10];
    const float* bat = (const float*)d_in[11];
    const float* Wsk = (const float*)d_in[12];
    const float* bsk = (const float*)d_in[13];
    const float* Wr  = (const float*)d_in[14];
    const float* br  = (const float*)d_in[15];
    const float* Wp1 = (const float*)d_in[16];
    const float* bp1 = (const float*)d_in[17];
    const float* Wp2 = (const float*)d_in[18];
    const float* bp2 = (const float*)d_in[19];
    float* dout = (float*)d_out;

    // ---- workspace layout (bytes) ----
    const size_t WG_EL  = (size_t)1024 * KGATE;       // gate packed elems/layer
    const size_t WSR_EL = (size_t)768 * KSR;
    char* w = (char*)d_ws;
    float*          out_tm = (float*)w;               w += (size_t)T_LEN * 512 * 4;          // 16.8 MB
    unsigned short* outhf  = (unsigned short*)w;      w += (size_t)(T_LEN + 512) * 512 * 2;  // 8.9 MB
    unsigned short* g_tm   = (unsigned short*)w;      w += (size_t)T_LEN * 512 * 2;          // 8.4 MB
    unsigned short* h_tm   = (unsigned short*)w;      w += (size_t)T_LEN * 64 * 2;           // 1.05 MB
    unsigned short* skiphf = (unsigned short*)w;      w += (size_t)T_LEN * 256 * 2;          // 4.2 MB
    unsigned short* o1hf   = (unsigned short*)w;      w += (size_t)T_LEN * 256 * 2;          // 4.2 MB
    unsigned short* Wp1_pk = (unsigned short*)w;      w += (size_t)256 * 256 * 2;
    unsigned short* Wp2_pk = (unsigned short*)w;      w += (size_t)256 * 256 * 2;
    unsigned short* Wg_pk  = (unsigned short*)w;      // per-layer: 2.23 MB; bulk: x30
    size_t used_base = (size_t)((char*)Wg_pk - (char*)d_ws);
    size_t need_bulk = used_base + (WG_EL + WSR_EL) * NLAYER * 2;
    const bool bulk = ws_size >= need_bulk;
    unsigned short* Wsr_pk = Wg_pk + (bulk ? WG_EL * NLAYER : WG_EL);
    float* skip = dout;                               // [8192][256] f32 accumulator

    hipMemsetAsync(skip, 0, (size_t)T_LEN * 256 * 4, stream);
    hipMemsetAsync(outhf, 0, (size_t)512 * 512 * 2, stream);

    embed_kernel2<<<(T_LEN * 512) / 256, 256, 0, stream>>>(x, Wc, bc, out_tm, outhf);
    packh_kernel<<<(T_LEN * 64) / 256, 256, 0, stream>>>(h, h_tm);
    pack_post_kernel<<<256, 256, 0, stream>>>(Wp1, Wp1_pk);
    pack_post_kernel<<<256, 256, 0, stream>>>(Wp2, Wp2_pk);

    if (bulk) {
        pack_gate_kernel<<<dim3(4352, NLAYER), 256, 0, stream>>>(Wds, Wdt, Was, Wat, Wg_pk);
        pack_sr_kernel<<<dim3(1536, NLAYER), 256, 0, stream>>>(Wsk, Wr, Wsr_pk);
    }

    for (int l = 0; l < NLAYER; ++l) {
        int dil = 1 << (l % 10);
        const unsigned short* wg;
        const unsigned short* wsr;
        if (bulk) {
            wg  = Wg_pk  + (size_t)l * WG_EL;
            wsr = Wsr_pk + (size_t)l * WSR_EL;
        } else {
            pack_gate_kernel<<<dim3(4352, 1), 256, 0, stream>>>(
                Wds + (size_t)l * RCH * RCH * 2, Wdt + (size_t)l * RCH * RCH * 2,
                Was + (size_t)l * RCH * ACH, Wat + (size_t)l * RCH * ACH, Wg_pk);
            pack_sr_kernel<<<dim3(1536, 1), 256, 0, stream>>>(
                Wsk + (size_t)l * SCH * RCH, Wr + (size_t)l * RCH * RCH, Wsr_pk);
            wg = Wg_pk; wsr = Wsr_pk;
        }
        mfma_gemm<0, KGATE / 64, 8><<<512, 256, 0, stream>>>(
            wg, outhf, h_tm,
            bds + (size_t)l * RCH, bdt + (size_t)l * RCH,
            bas + (size_t)l * RCH, bat + (size_t)l * RCH,
            nullptr, nullptr, g_tm, dil);
        mfma_gemm<1, KSR / 64, 6><<<384, 256, 0, stream>>>(
            wsr, g_tm, nullptr,
            bsk + (size_t)l * SCH, br + (size_t)l * RCH, nullptr, nullptr,
            skip, out_tm, outhf, 0);
    }

    reluconv_kernel<<<(T_LEN * 256) / 256, 256, 0, stream>>>(skip, skiphf);
    mfma_gemm<2, KPOST / 64, 2><<<128, 256, 0, stream>>>(
        Wp1_pk, skiphf, nullptr, bp1, nullptr, nullptr, nullptr,
        nullptr, nullptr, o1hf, 0);
    mfma_gemm<3, KPOST / 64, 2><<<128, 256, 0, stream>>>(
        Wp2_pk, o1hf, nullptr, bp2, nullptr, nullptr, nullptr,
        dout, nullptr, nullptr, 0);
}